// Round 6
// baseline (48.046 us; speedup 1.0000x reference)
//
#include <hip/hip_runtime.h>

// DynamicMaskHead: per-instance 3-layer 1x1-conv MLP over [rel_xy, feats] at
// 112x200, then AdelaiDet aligned_bilinear 2x upsample to [n,1,224,400].
// Fused single kernel; all intermediates stay in LDS.
//
// R6: weights moved to SGPRs via explicit readfirstlane (block-uniform values;
// scalar pipe, no VGPR pressure, no pins -- R3's pins caused scratch spill).
// Occupancy doubled: 512-thread blocks, launch_bounds(512,8) -> VGPR cap 64,
// 4 blocks/CU (36KB LDS) x 8 waves = 32 waves/CU (max). Math is bit-identical
// to R5 (absmax 1.95e-3).

#define IN_C   8
#define CHN    8
#define Hh     112
#define Ww     200
#define HWp    (Hh * Ww)
#define OH     224
#define OW     400
#define TY     16          // output rows per block
#define RL     9           // logit rows needed per tile (TY/2 + 1)
#define NPIX   (RL * Ww)   // 1800 logit px per tile
#define NPAIR  (NPIX / 2)  // 900
#define NTILES (OH / TY)   // 14
#define NPARAMS 169
#define BLK    512

typedef __fp16 f16x2 __attribute__((ext_vector_type(2)));

// force a block-uniform value into an SGPR
__device__ __forceinline__ float rfl(float x) {
    return __int_as_float(__builtin_amdgcn_readfirstlane(__float_as_int(x)));
}

// param layout per instance (169 floats):
// w0 [8][10] @0, w1 [8][8] @80, w2 [8] @144, b0 [8] @152, b1 [8] @160, b2 @168

__global__ __launch_bounds__(BLK, 8)
void dmh_fused_kernel(const float* __restrict__ feats,      // [4][8][112][200]
                      const float* __restrict__ params,     // [n][169]
                      const float* __restrict__ iloc,       // [n][2]
                      const float* __restrict__ soi_tab,    // [5]
                      const int*   __restrict__ im_inds,    // [n]
                      const int*   __restrict__ fpn_levels, // [n]
                      float* __restrict__ out)              // [n][224][400]
{
    __shared__ uint  h0s[CHN][NPAIR];  // post-ReLU h0, fp16x2 packed: 28.8 KB
    __shared__ float lgt[RL][Ww];      // logits: 7.2 KB

    const int bid  = blockIdx.x;
    const int inst = bid / NTILES;
    const int ty   = bid - inst * NTILES;
    const int y0   = ty * TY;
    const int r_lo = (y0 > 0 ? (y0 - 1) : 0) >> 1;   // first logit row of tile
    const int tid  = threadIdx.x;

    const float* __restrict__ wp = params + inst * NPARAMS;
    const float soi    = rfl(soi_tab[fpn_levels[inst]]);
    const float inv_s  = 1.0f / soi;
    const float ix     = rfl(iloc[inst * 2 + 0]);
    const float iy     = rfl(iloc[inst * 2 + 1]);
    const float* __restrict__ fb = feats + (size_t)im_inds[inst] * (IN_C * HWp);

    // ================= pass A: layer 0 -> h0 (fp16) in LDS =================
    {
        float w0r[80];
        #pragma unroll
        for (int i = 0; i < 80; i++) w0r[i] = rfl(wp[i]);
        float b0r[CHN];
        #pragma unroll
        for (int i = 0; i < CHN; i++) b0r[i] = rfl(wp[152 + i]);

        for (int g = tid; g < NPAIR; g += BLK) {
            const int rr = g / (Ww / 2);            // 0..8
            const int c2 = (g - rr * (Ww / 2)) * 2; // 0..198
            const int r  = r_lo + rr;               // <= 111
            const float* fp = fb + r * Ww + c2;

            float fv0[IN_C], fv1[IN_C];
            #pragma unroll
            for (int ch = 0; ch < IN_C; ch++) {
                const float2 t = *reinterpret_cast<const float2*>(fp + ch * HWp);
                fv0[ch] = t.x; fv1[ch] = t.y;
            }
            const float in1  = (iy - (float)(r * 8 + 4)) * inv_s;
            const float in00 = (ix - (float)(c2 * 8 + 4)) * inv_s;
            const float in01 = (ix - (float)(c2 * 8 + 12)) * inv_s;

            #pragma unroll
            for (int o = 0; o < CHN; o++) {
                const float bo = fmaf(w0r[o * 10 + 1], in1, b0r[o]);
                float t0 = fmaf(w0r[o * 10 + 0], in00, bo);
                float t1 = fmaf(w0r[o * 10 + 0], in01, bo);
                #pragma unroll
                for (int i = 0; i < IN_C; i++) {
                    t0 = fmaf(w0r[o * 10 + 2 + i], fv0[i], t0);
                    t1 = fmaf(w0r[o * 10 + 2 + i], fv1[i], t1);
                }
                t0 = fmaxf(t0, 0.0f);
                t1 = fmaxf(t1, 0.0f);
                const f16x2 pk = __builtin_amdgcn_cvt_pkrtz(t0, t1);
                h0s[o][g] = *reinterpret_cast<const uint*>(&pk);
            }
        }
    }
    __syncthreads();

    // ================= pass B: layers 1+2 -> logits in LDS =================
    {
        float w1r[64], w2r[CHN], b1r[CHN];
        #pragma unroll
        for (int i = 0; i < 64; i++) w1r[i] = rfl(wp[80 + i]);
        #pragma unroll
        for (int i = 0; i < CHN; i++) w2r[i] = rfl(wp[144 + i]);
        #pragma unroll
        for (int i = 0; i < CHN; i++) b1r[i] = rfl(wp[160 + i]);
        const float b2 = rfl(wp[168]);

        for (int g = tid; g < NPAIR; g += BLK) {
            float h00[CHN], h01[CHN];
            #pragma unroll
            for (int i = 0; i < CHN; i++) {
                const uint w = h0s[i][g];
                const f16x2 pk = *reinterpret_cast<const f16x2*>(&w);
                h00[i] = (float)pk.x;
                h01[i] = (float)pk.y;
            }
            float r0 = b2, r1 = b2;
            #pragma unroll
            for (int o = 0; o < CHN; o++) {
                float a0 = b1r[o];
                float a1 = a0;
                #pragma unroll
                for (int i = 0; i < CHN; i++) {
                    a0 = fmaf(w1r[o * 8 + i], h00[i], a0);
                    a1 = fmaf(w1r[o * 8 + i], h01[i], a1);
                }
                a0 = fmaxf(a0, 0.0f);
                a1 = fmaxf(a1, 0.0f);
                r0 = fmaf(w2r[o], a0, r0);
                r1 = fmaf(w2r[o], a1, r1);
            }
            const int rr = g / (Ww / 2);
            const int c2 = (g - rr * (Ww / 2)) * 2;
            *reinterpret_cast<float2*>(&lgt[rr][c2]) = make_float2(r0, r1);
        }
    }
    __syncthreads();

    // ============ pass C: aligned 2x bilinear, write 16x400 tile ============
    // out[y][x] = interp[max(y-1,0)][max(x-1,0)], axis weights {1} even / {.5,.5} odd
    float* __restrict__ ob = out + (size_t)inst * (OH * OW);
    const int NQ = (TY * OW) / 4;   // 1600 groups of 4 output px
    for (int q = tid; q < NQ; q += BLK) {
        const int dy = q / (OW / 4);            // 0..15
        const int gx = q - dy * (OW / 4);       // 0..99
        const int x  = gx * 4;
        const int y  = y0 + dy;
        const int i  = (y > 0 ? y - 1 : 0);
        const int rr0 = (i >> 1) - r_lo;
        const int r1g = (i >> 1) + (i & 1);
        const int rr1 = (r1g > Hh - 1 ? Hh - 1 : r1g) - r_lo;
        const float wy1 = (i & 1) ? 0.5f : 0.0f;
        const float wy0 = 1.0f - wy1;

        const int cx  = x >> 1;                 // 0..198 (x even)
        const int cm1 = (cx > 0 ? cx - 1 : 0);
        const float a_m = lgt[rr0][cm1], a_0 = lgt[rr0][cx], a_p = lgt[rr0][cx + 1];
        const float b_m = lgt[rr1][cm1], b_0 = lgt[rr1][cx], b_p = lgt[rr1][cx + 1];
        const float Rm = wy0 * a_m + wy1 * b_m;
        const float R0 = wy0 * a_0 + wy1 * b_0;
        const float Rp = wy0 * a_p + wy1 * b_p;

        float4 o4;
        o4.x = 0.5f * (Rm + R0);   // x+0: odd j (clamped at x=0 where Rm==R0)
        o4.y = R0;                 // x+1: exact col cx
        o4.z = 0.5f * (R0 + Rp);   // x+2: odd j
        o4.w = Rp;                 // x+3: exact col cx+1
        *reinterpret_cast<float4*>(&ob[y * OW + x]) = o4;
    }
}

extern "C" void kernel_launch(void* const* d_in, const int* in_sizes, int n_in,
                              void* d_out, int out_size, void* d_ws, size_t ws_size,
                              hipStream_t stream) {
    const float* mask_feats = (const float*)d_in[0];
    const float* params     = (const float*)d_in[1];
    const float* iloc       = (const float*)d_in[2];
    const float* soi        = (const float*)d_in[3];
    const int*   im_inds    = (const int*)d_in[4];
    const int*   fpn        = (const int*)d_in[5];
    // d_in[6] = mask_feat_stride (=8), baked into the kernel constants.
    float* out = (float*)d_out;

    const int n_inst = in_sizes[4];           // 200
    dim3 grid(n_inst * NTILES);               // 2800 blocks
    dim3 block(BLK);
    hipLaunchKernelGGL(dmh_fused_kernel, grid, block, 0, stream,
                       mask_feats, params, iloc, soi, im_inds, fpn, out);
}

// Round 7
// 39.349 us; speedup vs baseline: 1.2210x; 1.2210x over previous
//
#include <hip/hip_runtime.h>

// DynamicMaskHead: per-instance 3-layer 1x1-conv MLP over [rel_xy, feats] at
// 112x200, then AdelaiDet aligned_bilinear 2x upsample to [n,1,224,400].
// Fused single kernel; all intermediates stay in LDS.
//
// R7: weights pinned into SGPRs with asm "+s" (block-uniform scalars; FMA
// reads 1 SGPR operand legally; zero VGPR cost; pin is remat-opaque).
// R6 showed readfirstlane-without-pin -> per-use global_load+readfirstlane
// remat (VGPR=20, VALU-busy 38us); R6 also proved occupancy (67%) is NOT the
// limiter. With weights out of VGPRs, pass A/B widen to 4-px granularity:
// half the loop iterations, float4 feat loads, b64/b128 LDS staging.
// 256-thread blocks, launch_bounds(256,4); 36KB LDS -> 4 blocks/CU.

#define IN_C   8
#define CHN    8
#define Hh     112
#define Ww     200
#define HWp    (Hh * Ww)
#define OH     224
#define OW     400
#define TY     16          // output rows per block
#define RL     9           // logit rows needed per tile (TY/2 + 1)
#define NPIX   (RL * Ww)   // 1800 logit px per tile
#define NPAIR  (NPIX / 2)  // 900
#define NQUAD  (NPIX / 4)  // 450
#define NTILES (OH / TY)   // 14
#define NPARAMS 169
#define BLK    256

typedef __fp16 f16x2 __attribute__((ext_vector_type(2)));

// param layout per instance (169 floats):
// w0 [8][10] @0, w1 [8][8] @80, w2 [8] @144, b0 [8] @152, b1 [8] @160, b2 @168

__global__ __launch_bounds__(BLK, 4)
void dmh_fused_kernel(const float* __restrict__ feats,      // [4][8][112][200]
                      const float* __restrict__ params,     // [n][169]
                      const float* __restrict__ iloc,       // [n][2]
                      const float* __restrict__ soi_tab,    // [5]
                      const int*   __restrict__ im_inds,    // [n]
                      const int*   __restrict__ fpn_levels, // [n]
                      float* __restrict__ out)              // [n][224][400]
{
    __shared__ uint  h0s[CHN][NPAIR];  // post-ReLU h0, fp16x2 packed: 28.8 KB
    __shared__ float lgt[RL][Ww];      // logits: 7.2 KB

    const int bid  = blockIdx.x;
    const int inst = bid / NTILES;
    const int ty   = bid - inst * NTILES;
    const int y0   = ty * TY;
    const int r_lo = (y0 > 0 ? (y0 - 1) : 0) >> 1;   // first logit row of tile
    const int tid  = threadIdx.x;

    const float* __restrict__ wp = params + inst * NPARAMS;
    const float soi    = soi_tab[fpn_levels[inst]];
    const float inv_s  = 1.0f / soi;
    const float ix     = iloc[inst * 2 + 0];
    const float iy     = iloc[inst * 2 + 1];
    const float* __restrict__ fb = feats + (size_t)im_inds[inst] * (IN_C * HWp);

    // ================= pass A: layer 0 -> h0 (fp16) in LDS =================
    {
        float w0r[80], b0r[CHN];
        #pragma unroll
        for (int i = 0; i < 80; i++) w0r[i] = wp[i];
        #pragma unroll
        for (int i = 0; i < CHN; i++) b0r[i] = wp[152 + i];
        #pragma unroll
        for (int i = 0; i < 80; i++) asm volatile("" : "+s"(w0r[i]));
        #pragma unroll
        for (int i = 0; i < CHN; i++) asm volatile("" : "+s"(b0r[i]));

        for (int g = tid; g < NQUAD; g += BLK) {
            const int rr = g / (Ww / 4);            // 0..8
            const int c4 = (g - rr * (Ww / 4)) * 4; // 0..196
            const int r  = r_lo + rr;               // <= 111
            const float* fp = fb + r * Ww + c4;

            float fv[IN_C][4];
            #pragma unroll
            for (int ch = 0; ch < IN_C; ch++) {
                const float4 t = *reinterpret_cast<const float4*>(fp + ch * HWp);
                fv[ch][0] = t.x; fv[ch][1] = t.y; fv[ch][2] = t.z; fv[ch][3] = t.w;
            }
            const float in1 = (iy - (float)(r * 8 + 4)) * inv_s;
            float in0[4];
            #pragma unroll
            for (int k = 0; k < 4; k++)
                in0[k] = (ix - (float)((c4 + k) * 8 + 4)) * inv_s;

            #pragma unroll
            for (int o = 0; o < CHN; o++) {
                const float bo = fmaf(w0r[o * 10 + 1], in1, b0r[o]);
                float t0 = fmaf(w0r[o * 10 + 0], in0[0], bo);
                float t1 = fmaf(w0r[o * 10 + 0], in0[1], bo);
                float t2 = fmaf(w0r[o * 10 + 0], in0[2], bo);
                float t3 = fmaf(w0r[o * 10 + 0], in0[3], bo);
                #pragma unroll
                for (int i = 0; i < IN_C; i++) {
                    const float w = w0r[o * 10 + 2 + i];
                    t0 = fmaf(w, fv[i][0], t0);
                    t1 = fmaf(w, fv[i][1], t1);
                    t2 = fmaf(w, fv[i][2], t2);
                    t3 = fmaf(w, fv[i][3], t3);
                }
                const f16x2 pa = __builtin_amdgcn_cvt_pkrtz(fmaxf(t0, 0.0f), fmaxf(t1, 0.0f));
                const f16x2 pb = __builtin_amdgcn_cvt_pkrtz(fmaxf(t2, 0.0f), fmaxf(t3, 0.0f));
                uint2 u;
                u.x = *reinterpret_cast<const uint*>(&pa);
                u.y = *reinterpret_cast<const uint*>(&pb);
                *reinterpret_cast<uint2*>(&h0s[o][2 * g]) = u;   // ds_write_b64
            }
        }
    }
    __syncthreads();

    // ================= pass B: layers 1+2 -> logits in LDS =================
    {
        float w1r[64], w2r[CHN], b1r[CHN], b2;
        #pragma unroll
        for (int i = 0; i < 64; i++) w1r[i] = wp[80 + i];
        #pragma unroll
        for (int i = 0; i < CHN; i++) w2r[i] = wp[144 + i];
        #pragma unroll
        for (int i = 0; i < CHN; i++) b1r[i] = wp[160 + i];
        b2 = wp[168];
        #pragma unroll
        for (int i = 0; i < 64; i++) asm volatile("" : "+s"(w1r[i]));
        #pragma unroll
        for (int i = 0; i < CHN; i++) asm volatile("" : "+s"(w2r[i]));
        #pragma unroll
        for (int i = 0; i < CHN; i++) asm volatile("" : "+s"(b1r[i]));
        asm volatile("" : "+s"(b2));

        for (int g = tid; g < NQUAD; g += BLK) {
            float h[IN_C][4];
            #pragma unroll
            for (int i = 0; i < CHN; i++) {
                const uint2 u = *reinterpret_cast<const uint2*>(&h0s[i][2 * g]); // ds_read_b64
                const f16x2 pa = *reinterpret_cast<const f16x2*>(&u.x);
                const f16x2 pb = *reinterpret_cast<const f16x2*>(&u.y);
                h[i][0] = (float)pa.x; h[i][1] = (float)pa.y;
                h[i][2] = (float)pb.x; h[i][3] = (float)pb.y;
            }
            float r0 = b2, r1 = b2, r2 = b2, r3 = b2;
            #pragma unroll
            for (int o = 0; o < CHN; o++) {
                float a0 = b1r[o], a1 = b1r[o], a2 = b1r[o], a3 = b1r[o];
                #pragma unroll
                for (int i = 0; i < CHN; i++) {
                    const float w = w1r[o * 8 + i];
                    a0 = fmaf(w, h[i][0], a0);
                    a1 = fmaf(w, h[i][1], a1);
                    a2 = fmaf(w, h[i][2], a2);
                    a3 = fmaf(w, h[i][3], a3);
                }
                const float w2 = w2r[o];
                r0 = fmaf(w2, fmaxf(a0, 0.0f), r0);
                r1 = fmaf(w2, fmaxf(a1, 0.0f), r1);
                r2 = fmaf(w2, fmaxf(a2, 0.0f), r2);
                r3 = fmaf(w2, fmaxf(a3, 0.0f), r3);
            }
            const int rr = g / (Ww / 4);
            const int c4 = (g - rr * (Ww / 4)) * 4;
            *reinterpret_cast<float4*>(&lgt[rr][c4]) =
                make_float4(r0, r1, r2, r3);                     // ds_write_b128
        }
    }
    __syncthreads();

    // ============ pass C: aligned 2x bilinear, write 16x400 tile ============
    // out[y][x] = interp[max(y-1,0)][max(x-1,0)], axis weights {1} even / {.5,.5} odd
    float* __restrict__ ob = out + (size_t)inst * (OH * OW);
    const int NQ = (TY * OW) / 4;   // 1600 groups of 4 output px
    for (int q = tid; q < NQ; q += BLK) {
        const int dy = q / (OW / 4);            // 0..15
        const int gx = q - dy * (OW / 4);       // 0..99
        const int x  = gx * 4;
        const int y  = y0 + dy;
        const int i  = (y > 0 ? y - 1 : 0);
        const int rr0 = (i >> 1) - r_lo;
        const int r1g = (i >> 1) + (i & 1);
        const int rr1 = (r1g > Hh - 1 ? Hh - 1 : r1g) - r_lo;
        const float wy1 = (i & 1) ? 0.5f : 0.0f;
        const float wy0 = 1.0f - wy1;

        const int cx  = x >> 1;                 // 0..198 (x even)
        const int cm1 = (cx > 0 ? cx - 1 : 0);
        const float a_m = lgt[rr0][cm1], a_0 = lgt[rr0][cx], a_p = lgt[rr0][cx + 1];
        const float b_m = lgt[rr1][cm1], b_0 = lgt[rr1][cx], b_p = lgt[rr1][cx + 1];
        const float Rm = wy0 * a_m + wy1 * b_m;
        const float R0 = wy0 * a_0 + wy1 * b_0;
        const float Rp = wy0 * a_p + wy1 * b_p;

        float4 o4;
        o4.x = 0.5f * (Rm + R0);   // x+0: odd j (clamped at x=0 where Rm==R0)
        o4.y = R0;                 // x+1: exact col cx
        o4.z = 0.5f * (R0 + Rp);   // x+2: odd j
        o4.w = Rp;                 // x+3: exact col cx+1
        *reinterpret_cast<float4*>(&ob[y * OW + x]) = o4;
    }
}

extern "C" void kernel_launch(void* const* d_in, const int* in_sizes, int n_in,
                              void* d_out, int out_size, void* d_ws, size_t ws_size,
                              hipStream_t stream) {
    const float* mask_feats = (const float*)d_in[0];
    const float* params     = (const float*)d_in[1];
    const float* iloc       = (const float*)d_in[2];
    const float* soi        = (const float*)d_in[3];
    const int*   im_inds    = (const int*)d_in[4];
    const int*   fpn        = (const int*)d_in[5];
    // d_in[6] = mask_feat_stride (=8), baked into the kernel constants.
    float* out = (float*)d_out;

    const int n_inst = in_sizes[4];           // 200
    dim3 grid(n_inst * NTILES);               // 2800 blocks
    dim3 block(BLK);
    hipLaunchKernelGGL(dmh_fused_kernel, grid, block, 0, stream,
                       mask_feats, params, iloc, soi, im_inds, fpn, out);
}